// Round 6
// baseline (494.645 us; speedup 1.0000x reference)
//
#include <hip/hip_runtime.h>
#include <hip/hip_bf16.h>
#include <stdint.h>

#define D_IN 256
#define NEG 0.2f

typedef unsigned short bf16_t;
typedef __attribute__((ext_vector_type(8))) short bfrag;   // 8 bf16 = 4 VGPR
typedef __attribute__((ext_vector_type(4))) float ffrag;   // MFMA C/D
typedef float f32x2 __attribute__((ext_vector_type(2)));   // packed fp32 (v_pk_*)

__device__ __forceinline__ bf16_t f2bf(float f) {
  unsigned int u = __float_as_uint(f);
  unsigned int r = u + 0x7FFFu + ((u >> 16) & 1u);   // RNE
  return (bf16_t)(r >> 16);
}
__device__ __forceinline__ unsigned int pk2(float a, float b) {
  return (unsigned int)f2bf(a) | ((unsigned int)f2bf(b) << 16);
}
// 4 bf16 -> 2 packed f32x2
__device__ __forceinline__ void ldv(const bf16_t* p, f32x2& a, f32x2& b) {
  uint2 u = *(const uint2*)p;
  a[0] = __uint_as_float(u.x << 16);
  a[1] = __uint_as_float(u.x & 0xFFFF0000u);
  b[0] = __uint_as_float(u.y << 16);
  b[1] = __uint_as_float(u.y & 0xFFFF0000u);
}

// ---------------- K0: zero deg  UNION  Wt transpose+convert ----------------
__global__ __launch_bounds__(256) void k_zero_wt(int* __restrict__ deg, int n, int zb,
                                                 const float* __restrict__ Wl,
                                                 const float* __restrict__ Wr,
                                                 bf16_t* __restrict__ Wt) {
  const int b = blockIdx.x, tid = threadIdx.x;
  if (b < zb) {
    int i = b * 256 + tid;
    if (i < n) deg[i] = 0;
  } else {
    int gid = (b - zb) * 256 + tid;   // 2*256*256 total
    int w = gid >> 16;
    int c = (gid >> 8) & 255;
    int k = gid & 255;
    const float* W = w ? Wr : Wl;
    Wt[gid] = f2bf(W[k * 256 + c]);
  }
}

// ---------------- K_A: hist(+rank)  UNION  emb fp32->bf16 conv ----------------
__global__ __launch_bounds__(256) void k_hist_conv(const int* __restrict__ dst, int E,
                                                   int* __restrict__ deg, int* __restrict__ rank,
                                                   int hb,
                                                   const float* __restrict__ emb,
                                                   bf16_t* __restrict__ embh, int n4) {
  const int b = blockIdx.x, tid = threadIdx.x;
  if (b < hb) {
    int e = b * 256 + tid;
    if (e < E) rank[e] = atomicAdd(&deg[dst[e]], 1);
  } else {
    int i = (b - hb) * 256 + tid;
    if (i < n4) {
      float4 f = ((const float4*)emb)[i];
      uint2 o;
      o.x = pk2(f.x, f.y);
      o.y = pk2(f.z, f.w);
      ((uint2*)embh)[i] = o;
    }
  }
}

// ---------------- scanA: per-1024-chunk exclusive prefix + chunk totals ----------------
__global__ __launch_bounds__(256) void k_scanA(const int* __restrict__ deg,
                                               int* __restrict__ offs,
                                               int* __restrict__ bsum, int N) {
  __shared__ int sh[256];
  int t = threadIdx.x;
  int base = blockIdx.x * 1024 + t * 4;
  int v[4];
#pragma unroll
  for (int q = 0; q < 4; q++) v[q] = (base + q < N) ? deg[base + q] : 0;
  int ls = v[0] + v[1] + v[2] + v[3];
  sh[t] = ls;
  __syncthreads();
  for (int ofs = 1; ofs < 256; ofs <<= 1) {
    int x = (t >= ofs) ? sh[t - ofs] : 0;
    __syncthreads();
    sh[t] += x;
    __syncthreads();
  }
  int run = sh[t] - ls;
#pragma unroll
  for (int q = 0; q < 4; q++) {
    if (base + q < N) offs[base + q] = run;
    run += v[q];
  }
  if (t == 255) bsum[blockIdx.x] = sh[255];
}

// ---------------- scanBC: each block reduces its prefix of bsum, adds ----------------
__global__ __launch_bounds__(256) void k_scanBC(int* __restrict__ offs,
                                                const int* __restrict__ bsum, int N, int E) {
  const int b = blockIdx.x, t = threadIdx.x;
  const int wv = t >> 6, lane = t & 63;
  __shared__ int ws[4];
  int v = (t < b) ? bsum[t] : 0;   // nb <= 256
  v += __shfl_xor(v, 1);  v += __shfl_xor(v, 2);  v += __shfl_xor(v, 4);
  v += __shfl_xor(v, 8);  v += __shfl_xor(v, 16); v += __shfl_xor(v, 32);
  if (lane == 0) ws[wv] = v;
  __syncthreads();
  const int add = ws[0] + ws[1] + ws[2] + ws[3];
  int base = b * 1024 + t * 4;
#pragma unroll
  for (int q = 0; q < 4; q++) {
    int i = base + q;
    if (i < N) offs[i] += add;
  }
  if (b == 0 && t == 0) offs[N] = E;
}

// ---------------- K_E: MFMA GEMM  UNION  scatter (no atomic) ----------------
template <bool USEBF>
__global__ __launch_bounds__(256) void k_gemm_scatter(
    const float* __restrict__ emb, const bf16_t* __restrict__ embh,
    const bf16_t* __restrict__ Wt, bf16_t* __restrict__ xl, bf16_t* __restrict__ xr,
    const int* __restrict__ src, const int* __restrict__ dst,
    const int* __restrict__ offs, const int* __restrict__ rank, int* __restrict__ csr,
    int N, int E, int gb) {
  __shared__ bf16_t As[128][40];
  __shared__ bf16_t Bs[128][40];
  const int tid = threadIdx.x;

  if ((int)blockIdx.x >= gb) {   // -------- scatter branch --------
    int e = ((int)blockIdx.x - gb) * 256 + tid;
    if (e < E) {
      int pos = offs[dst[e]] + rank[e];
      csr[pos] = src[e];
    }
    return;
  }

  // -------- gemm branch --------
  const int bx = blockIdx.x >> 2, nt = blockIdx.x & 3;  // nt: 0,1->Wl; 2,3->Wr
  const int row0 = bx * 128;
  const bf16_t* Wp = Wt + (size_t)(nt >> 1) * 65536;
  bf16_t* dstp = (nt < 2) ? xl : xr;
  const int c0 = (nt & 1) * 128;

  const int wave = tid >> 6, lane = tid & 63;
  const int m0w = (wave & 1) * 64, n0w = (wave >> 1) * 64;
  const int fr = lane & 15;
  const int aq = (lane >> 4) * 8;

  const int srow = tid >> 1, sseg = (tid & 1) * 16;
  const int grow = row0 + srow;
  const bool aok = grow < N;
  const bf16_t* bp = Wp + (size_t)(c0 + srow) * 256 + sseg;

  ffrag acc[4][4];
#pragma unroll
  for (int mi = 0; mi < 4; mi++)
#pragma unroll
    for (int ni = 0; ni < 4; ni++) acc[mi][ni] = (ffrag)0.f;

  for (int k0 = 0; k0 < 256; k0 += 32) {
    uint4 pa0 = make_uint4(0, 0, 0, 0), pa1 = pa0;
    if (USEBF) {
      const bf16_t* ap = embh + (size_t)grow * 256 + sseg;
      if (aok) {
        pa0 = *(const uint4*)(ap + k0);
        pa1 = *(const uint4*)(ap + k0 + 8);
      }
    } else {
      const float* ap = emb + (size_t)grow * 256 + sseg;
      float4 f0 = make_float4(0, 0, 0, 0), f1 = f0, f2 = f0, f3 = f0;
      if (aok) {
        f0 = *(const float4*)(ap + k0);
        f1 = *(const float4*)(ap + k0 + 4);
        f2 = *(const float4*)(ap + k0 + 8);
        f3 = *(const float4*)(ap + k0 + 12);
      }
      pa0.x = pk2(f0.x, f0.y); pa0.y = pk2(f0.z, f0.w);
      pa0.z = pk2(f1.x, f1.y); pa0.w = pk2(f1.z, f1.w);
      pa1.x = pk2(f2.x, f2.y); pa1.y = pk2(f2.z, f2.w);
      pa1.z = pk2(f3.x, f3.y); pa1.w = pk2(f3.z, f3.w);
    }
    uint4 b0 = *(const uint4*)(bp + k0);
    uint4 b1 = *(const uint4*)(bp + k0 + 8);
    __syncthreads();
    *(uint4*)&As[srow][sseg] = pa0;
    *(uint4*)&As[srow][sseg + 8] = pa1;
    *(uint4*)&Bs[srow][sseg] = b0;
    *(uint4*)&Bs[srow][sseg + 8] = b1;
    __syncthreads();

    bfrag af[4], bfv[4];
#pragma unroll
    for (int mi = 0; mi < 4; mi++) af[mi] = *(const bfrag*)&As[m0w + mi * 16 + fr][aq];
#pragma unroll
    for (int ni = 0; ni < 4; ni++) bfv[ni] = *(const bfrag*)&Bs[n0w + ni * 16 + fr][aq];
#pragma unroll
    for (int mi = 0; mi < 4; mi++)
#pragma unroll
      for (int ni = 0; ni < 4; ni++)
        acc[mi][ni] = __builtin_amdgcn_mfma_f32_16x16x32_bf16(af[mi], bfv[ni], acc[mi][ni], 0, 0, 0);
  }

  const int rbase = m0w + (lane >> 4) * 4;
#pragma unroll
  for (int mi = 0; mi < 4; mi++) {
#pragma unroll
    for (int ni = 0; ni < 4; ni++) {
      int col = c0 + n0w + ni * 16 + fr;
#pragma unroll
      for (int r = 0; r < 4; r++) {
        int row = row0 + rbase + mi * 16 + r;
        if (row < N) dstp[(size_t)row * 256 + col] = f2bf(acc[mi][ni][r]);
      }
    }
  }
}

// ---------------- fused edge pass: packed-fp32, batch-8 ----------------
// one wave per dst node; lane = (head = lane>>4) x (4-ch group = lane&15)
// plain exp (no max-sub): scores tiny, overflow impossible — validated R4/R5.
__device__ __forceinline__ float wred16(float p) {
  p += __shfl_xor(p, 1);
  p += __shfl_xor(p, 2);
  p += __shfl_xor(p, 4);
  p += __shfl_xor(p, 8);
  return p;
}

__global__ __launch_bounds__(256) void k_edge(const bf16_t* __restrict__ xl,
                                              const bf16_t* __restrict__ xr,
                                              const int* __restrict__ offs,
                                              const int* __restrict__ csr,
                                              const float* __restrict__ att,
                                              const float* __restrict__ bias,
                                              float* __restrict__ out, int N) {
  const int wv = threadIdx.x >> 6;
  const int lane = threadIdx.x & 63;
  const int i = blockIdx.x * 4 + wv;
  if (i >= N) return;
  const int cbase = (lane >> 4) * 64 + (lane & 15) * 4;
  const bf16_t* xlc = xl + cbase;   // lane-fixed channel base

  f32x2 av0, av1;
  {
    float4 t = *(const float4*)(att + cbase);
    av0[0] = t.x; av0[1] = t.y; av1[0] = t.z; av1[1] = t.w;
  }
  f32x2 xr0, xr1;
  ldv(xr + (size_t)i * 256 + cbase, xr0, xr1);

  f32x2 acc0, acc1;
  float d;
  {  // self loop
    f32x2 x0, x1;
    ldv(xlc + i * 256, x0, x1);
    f32x2 t0 = x0 + xr0, t1 = x1 + xr1;
    t0 = __builtin_elementwise_max(t0, t0 * NEG);
    t1 = __builtin_elementwise_max(t1, t1 * NEG);
    f32x2 p = av0 * t0;
    p = __builtin_elementwise_fma(av1, t1, p);
    float e = __expf(wred16(p[0] + p[1]));
    d = e;
    f32x2 ev = {e, e};
    acc0 = x0 * ev;
    acc1 = x1 * ev;
  }

  int k = offs[i];
  const int kend = offs[i + 1];

  for (; k + 8 <= kend; k += 8) {
    f32x2 x0[8], x1[8];
    float s[8];
#pragma unroll
    for (int q = 0; q < 8; q++) {
      int j = csr[k + q];
      ldv(xlc + j * 256, x0[q], x1[q]);
    }
#pragma unroll
    for (int q = 0; q < 8; q++) {
      f32x2 t0 = x0[q] + xr0, t1 = x1[q] + xr1;
      t0 = __builtin_elementwise_max(t0, t0 * NEG);
      t1 = __builtin_elementwise_max(t1, t1 * NEG);
      f32x2 p = av0 * t0;
      p = __builtin_elementwise_fma(av1, t1, p);
      s[q] = p[0] + p[1];
    }
#pragma unroll
    for (int q = 0; q < 8; q++) s[q] = wred16(s[q]);
#pragma unroll
    for (int q = 0; q < 8; q++) {
      float e = __expf(s[q]);
      d += e;
      f32x2 ev = {e, e};
      acc0 = __builtin_elementwise_fma(x0[q], ev, acc0);
      acc1 = __builtin_elementwise_fma(x1[q], ev, acc1);
    }
  }
  for (; k < kend; ++k) {
    int j = csr[k];
    f32x2 x0, x1;
    ldv(xlc + j * 256, x0, x1);
    f32x2 t0 = x0 + xr0, t1 = x1 + xr1;
    t0 = __builtin_elementwise_max(t0, t0 * NEG);
    t1 = __builtin_elementwise_max(t1, t1 * NEG);
    f32x2 p = av0 * t0;
    p = __builtin_elementwise_fma(av1, t1, p);
    float e = __expf(wred16(p[0] + p[1]));
    d += e;
    f32x2 ev = {e, e};
    acc0 = __builtin_elementwise_fma(x0, ev, acc0);
    acc1 = __builtin_elementwise_fma(x1, ev, acc1);
  }

  const float inv = 0.25f / d;  // per-head 1/denom * head-mean
  float v[4] = {acc0[0] * inv, acc0[1] * inv, acc1[0] * inv, acc1[1] * inv};
#pragma unroll
  for (int q = 0; q < 4; q++) {
    v[q] += __shfl_xor(v[q], 16);
    v[q] += __shfl_xor(v[q], 32);
  }
  if ((lane >> 4) == 0) {
    const float4 bq = *(const float4*)(bias + (lane & 15) * 4);
    const float bb[4] = {bq.x, bq.y, bq.z, bq.w};
    float o[4];
#pragma unroll
    for (int q = 0; q < 4; q++) {
      float x = v[q] + bb[q];
      o[q] = x > 0.f ? x : (__expf(x) - 1.f);  // elu
    }
    *(float4*)(out + (size_t)i * 64 + (lane & 15) * 4) = make_float4(o[0], o[1], o[2], o[3]);
  }
}

extern "C" void kernel_launch(void* const* d_in, const int* in_sizes, int n_in,
                              void* d_out, int out_size, void* d_ws, size_t ws_size,
                              hipStream_t stream) {
  const int* edge = (const int*)d_in[1];   // [2][E] : row0 = src, row1 = dst
  const float* emb = (const float*)d_in[2];
  const float* Wl = (const float*)d_in[3];
  const float* Wr = (const float*)d_in[4];
  const float* att = (const float*)d_in[5];
  const float* bias = (const float*)d_in[6];
  float* out = (float*)d_out;

  const int E = in_sizes[1] / 2;
  const int N = in_sizes[2] / D_IN;
  const int* src = edge;
  const int* dst = edge + E;

  // strictly disjoint carve; embh (gated) at the end
  const size_t NB = (size_t)N * 256 * 2;
  char* w = (char*)d_ws;
  bf16_t* xl = (bf16_t*)w;  w += NB;
  bf16_t* xr = (bf16_t*)w;  w += NB;
  bf16_t* Wt = (bf16_t*)w;  w += (size_t)2 * 256 * 256 * 2;
  int* offs = (int*)w;      w += ((size_t)N + 64) * 4;
  int* deg = (int*)w;       w += ((size_t)N + 64) * 4;
  int* bsum = (int*)w;      w += 1024;
  int* rank = (int*)w;      w += (size_t)E * 4;
  int* csr = (int*)w;       w += (size_t)E * 4;
  bf16_t* embh = (bf16_t*)w;
  const size_t need_big = (size_t)(w - (char*)d_ws) + NB;
  const bool big = ws_size >= need_big;   // ws_size constant -> same path every call

  const int nb = (N + 1023) / 1024;
  const int zb = (N + 255) / 256;
  const int hb = (E + 255) / 256;
  const int n4 = big ? N * 64 : 0;
  const int cb = big ? (n4 + 255) / 256 : 0;
  const int gb = ((N + 127) / 128) * 4;
  const int sb = hb;

  hipLaunchKernelGGL(k_zero_wt, dim3(zb + 512), dim3(256), 0, stream, deg, N, zb, Wl, Wr, Wt);
  hipLaunchKernelGGL(k_hist_conv, dim3(hb + cb), dim3(256), 0, stream, dst, E, deg, rank, hb,
                     emb, embh, n4);
  hipLaunchKernelGGL(k_scanA, dim3(nb), dim3(256), 0, stream, deg, offs, bsum, N);
  hipLaunchKernelGGL(k_scanBC, dim3(nb), dim3(256), 0, stream, offs, bsum, N, E);
  if (big) {
    hipLaunchKernelGGL(k_gemm_scatter<true>, dim3(gb + sb), dim3(256), 0, stream,
                       emb, embh, Wt, xl, xr, src, dst, offs, rank, csr, N, E, gb);
  } else {
    hipLaunchKernelGGL(k_gemm_scatter<false>, dim3(gb + sb), dim3(256), 0, stream,
                       emb, embh, Wt, xl, xr, src, dst, offs, rank, csr, N, E, gb);
  }
  hipLaunchKernelGGL(k_edge, dim3((N + 3) / 4), dim3(256), 0, stream, xl, xr, offs, csr,
                     att, bias, out, N);
}